// Round 4
// baseline (138.995 us; speedup 1.0000x reference)
//
#include <hip/hip_runtime.h>

// Problem constants (fixed by the reference): B=16 lists, N=1024, D=256.
#define BL 16
#define NL 1024
#define DD 256
#define KSTEPS 8   // 256 / 32

typedef short bf16x8 __attribute__((ext_vector_type(8)));
typedef float f32x4 __attribute__((ext_vector_type(4)));

static __device__ __forceinline__ short f32_to_bf16(float f) {
  union { float f; unsigned u; } v; v.f = f;
  unsigned r = (v.u + 0x7FFFu + ((v.u >> 16) & 1u)) >> 16;  // RNE
  return (short)r;
}

// Async 16B global->LDS. Dest is wave-uniform base + lane*16 (m104/m108).
static __device__ __forceinline__ void g2l16(const short* g, short* l) {
  __builtin_amdgcn_global_load_lds(
      (const __attribute__((address_space(1))) void*)g,
      (__attribute__((address_space(3))) void*)l, 16, 0, 0);
}

// GLOBAL LAYOUT (Xb/WT/Y): row-major [rows][256], but within each 32-wide
// k-panel the four 16B chunks are XOR-swizzled: stored chunk = c ^ ((row>>1)&3).
// g2l16's lane-linear copy then lands a swizzled LDS image -> frag reads are
// 2-way-conflict only (free, m136) instead of 8-way (2.94x).

// Stage one 128x32 swizzled panel into LDS [128][32] (row stride 64B).
// Thread t: row=t>>2, chunk=t&3; LDS off = i*4096B + t*16B (lane-linear).
static __device__ __forceinline__ void stage_tile(const short* __restrict__ gbase,
                                                  short* __restrict__ lds,
                                                  int t, int k0) {
  const int row = t >> 2, kc = t & 3;
#pragma unroll
  for (int i = 0; i < 2; ++i) {
    const short* g = gbase + (size_t)(row + 64 * i) * DD + k0 + kc * 8;
    g2l16(g, lds + i * 2048 + t * 8);
  }
}

// One 32-wide k step: 8 ds_read_b128 + 16 MFMA. Wave computes 64x64 at (wm,wn).
// Frag read undoes the panel swizzle: chunk = quad ^ ((r>>1)&3).
static __device__ __forceinline__ void mma_step(const short* __restrict__ As,
                                                const short* __restrict__ Bs,
                                                int wm, int wn, int r, int quad,
                                                f32x4 acc[4][4]) {
  const int ch = (quad ^ ((r >> 1) & 3)) * 8;
  bf16x8 af[4], bf[4];
#pragma unroll
  for (int i = 0; i < 4; ++i) {
    af[i] = *(const bf16x8*)(As + (wm + i * 16 + r) * 32 + ch);
    bf[i] = *(const bf16x8*)(Bs + (wn + i * 16 + r) * 32 + ch);
  }
#pragma unroll
  for (int mt = 0; mt < 4; ++mt)
#pragma unroll
    for (int nt = 0; nt < 4; ++nt)
      acc[mt][nt] = __builtin_amdgcn_mfma_f32_16x16x32_bf16(af[mt], bf[nt], acc[mt][nt], 0, 0, 0);
}

// Swizzled flat offset for element (row, k) in a [rows][256] array.
static __device__ __forceinline__ size_t sw_off(int row, int k) {
  const int panel = k >> 5, c = (k >> 3) & 3, j = k & 7;
  const int s = (row >> 1) & 3;
  return (size_t)row * DD + panel * 32 + ((c ^ s) * 8) + j;
}

// ---- Kernel 1: prep. Blocks [0,2048): X fp32->bf16 (swizzled chunks).
//                 Blocks [2048,2560): W transpose (swizzled).
__global__ __launch_bounds__(256) void k_prep(const float* __restrict__ X,
                                              const float* __restrict__ Wu,
                                              const float* __restrict__ Wl,
                                              short* __restrict__ Xb,
                                              short* __restrict__ WTu,
                                              short* __restrict__ WTl) {
  const int bid = blockIdx.x;
  if (bid < 2048) {
    // One 16B chunk (8 bf16) per thread; 16384 rows x 32 chunks.
    const int i = bid * 256 + threadIdx.x;
    const int row = i >> 5, c32 = i & 31;
    const int panel = c32 >> 2, c = c32 & 3;
    const float4* src = (const float4*)(X + (size_t)row * DD + panel * 32 + c * 8);
    const float4 v0 = src[0], v1 = src[1];
    short o[8] = {f32_to_bf16(v0.x), f32_to_bf16(v0.y), f32_to_bf16(v0.z), f32_to_bf16(v0.w),
                  f32_to_bf16(v1.x), f32_to_bf16(v1.y), f32_to_bf16(v1.z), f32_to_bf16(v1.w)};
    const int s = (row >> 1) & 3;
    *(bf16x8*)(Xb + (size_t)row * DD + panel * 32 + ((c ^ s) * 8)) = *(bf16x8*)o;
  } else {
    const int id = bid - 2048;            // [0,512)
    const int z = id >> 8, d = id & 255;  // matrix, source row (k index)
    const float* W = z ? Wl : Wu;
    short* WT = z ? WTl : WTu;
    const int e = threadIdx.x;            // dest row
    WT[sw_off(e, d)] = f32_to_bf16(W[d * DD + e]);
  }
}

// ---- Kernel 2: stage 1 GEMM  Y = Xb * W  (Y[m][n] = sum_k Xb[m][k]*WT[n][k])
// 128x128 tile, BK=32, single-barrier pipelined K-loop.
__global__ __launch_bounds__(256) void k_stage1(const short* __restrict__ Xb,
                                                const short* __restrict__ WTu,
                                                const short* __restrict__ WTl,
                                                short* __restrict__ YU,
                                                short* __restrict__ YL) {
  __shared__ short As[2][128 * 32], Bs[2][128 * 32];
  const short* Bt = blockIdx.z ? WTl : WTu;
  short* Y = blockIdx.z ? YL : YU;
  const int m0 = blockIdx.y * 128, n0 = blockIdx.x * 128;
  const int t = threadIdx.x, lane = t & 63, wave = t >> 6;
  const int r = lane & 15, quad = lane >> 4;
  const int wm = (wave >> 1) * 64, wn = (wave & 1) * 64;
  f32x4 acc[4][4] = {};
  const short* Ag = Xb + (size_t)m0 * DD;
  const short* Bg = Bt + (size_t)n0 * DD;
  stage_tile(Ag, As[0], t, 0);
  stage_tile(Bg, Bs[0], t, 0);
  for (int i = 0; i < KSTEPS; ++i) {
    __syncthreads();                       // drains pf(i); mma(i-1) done
    if (i + 1 < KSTEPS) {                  // prefetch next while computing
      stage_tile(Ag, As[(i + 1) & 1], t, (i + 1) * 32);
      stage_tile(Bg, Bs[(i + 1) & 1], t, (i + 1) * 32);
    }
    mma_step(As[i & 1], Bs[i & 1], wm, wn, r, quad, acc);
  }
#pragma unroll
  for (int mt = 0; mt < 4; ++mt)
#pragma unroll
    for (int nt = 0; nt < 4; ++nt)
#pragma unroll
      for (int i = 0; i < 4; ++i)
        Y[sw_off(m0 + wm + mt * 16 + quad * 4 + i, n0 + wn + nt * 16 + r)] =
            f32_to_bf16(acc[mt][nt][i]);
}

// ---- Kernel 3: stage 2 merged (64 tiles x 16 lists).
// Off-diagonal: 1 pass. Diagonal: 2 passes (U then L), predicated stores.
__global__ __launch_bounds__(256) void k_stage2(const short* __restrict__ Xb,
                                                const short* __restrict__ YU,
                                                const short* __restrict__ YL,
                                                const float* __restrict__ bu_p,
                                                const float* __restrict__ bl_p,
                                                float* __restrict__ out) {
  __shared__ short As[2][128 * 32], Bs[2][128 * 32];
  const int pt = blockIdx.x >> 3, qt = blockIdx.x & 7, b = blockIdx.y;
  const size_t off = (size_t)b * NL * DD;
  const short* Bg = Xb + off + (size_t)qt * 128 * DD;
  const int t = threadIdx.x, lane = t & 63, wave = t >> 6;
  const int r = lane & 15, quad = lane >> 4;
  const int wm = (wave >> 1) * 64, wn = (wave & 1) * 64;
  float* Ob = out + (size_t)b * NL * NL;
  const int p0 = pt * 128 + wm, q0 = qt * 128 + wn;
  const float bu = bu_p[0], bl = bl_p[0];
  const bool diag = (pt == qt);
  const int npass = diag ? 2 : 1;

  for (int pass = 0; pass < npass; ++pass) {
    const bool useU = diag ? (pass == 0) : (qt > pt);
    const short* Ag = (useU ? YU : YL) + off + (size_t)pt * 128 * DD;
    const float bias = useU ? bu : bl;
    const f32x4 binit = {bias, bias, bias, bias};
    f32x4 acc[4][4];
#pragma unroll
    for (int mt = 0; mt < 4; ++mt)
#pragma unroll
      for (int nt = 0; nt < 4; ++nt) acc[mt][nt] = binit;

    __syncthreads();                       // pass>0: prior mma done before restage
    stage_tile(Ag, As[0], t, 0);
    stage_tile(Bg, Bs[0], t, 0);
    for (int i = 0; i < KSTEPS; ++i) {
      __syncthreads();
      if (i + 1 < KSTEPS) {
        stage_tile(Ag, As[(i + 1) & 1], t, (i + 1) * 32);
        stage_tile(Bg, Bs[(i + 1) & 1], t, (i + 1) * 32);
      }
      mma_step(As[i & 1], Bs[i & 1], wm, wn, r, quad, acc);
    }
    // Store: off-diag all; diag pass0 q>=p, pass1 q<p.
#pragma unroll
    for (int mt = 0; mt < 4; ++mt)
#pragma unroll
      for (int nt = 0; nt < 4; ++nt)
#pragma unroll
        for (int i = 0; i < 4; ++i) {
          const int p = p0 + mt * 16 + quad * 4 + i;
          const int q = q0 + nt * 16 + r;
          if (!diag || (pass == 0 ? (q >= p) : (q < p)))
            Ob[(size_t)p * NL + q] = acc[mt][nt][i];
        }
  }
}

extern "C" void kernel_launch(void* const* d_in, const int* in_sizes, int n_in,
                              void* d_out, int out_size, void* d_ws, size_t ws_size,
                              hipStream_t stream) {
  const float* feats = (const float*)d_in[0];   // [B*N, D] fp32
  const float* Wu    = (const float*)d_in[1];   // [1, D, D]
  const float* bu    = (const float*)d_in[2];   // [1]
  const float* Wl    = (const float*)d_in[3];   // [1, D, D]
  const float* bl    = (const float*)d_in[4];   // [1]
  float* out = (float*)d_out;                   // [B, N, N] fp32

  char* ws = (char*)d_ws;
  short* Xb  = (short*)(ws);                                   // 8 MB
  short* YU  = (short*)(ws + (size_t)8 * 1024 * 1024);         // 8 MB
  short* YL  = (short*)(ws + (size_t)16 * 1024 * 1024);        // 8 MB
  short* WTu = (short*)(ws + (size_t)24 * 1024 * 1024);        // 128 KB
  short* WTl = (short*)(ws + (size_t)24 * 1024 * 1024 + DD * DD * 2);

  // Prep: X->bf16 swizzled (2048 blocks) + W transpose swizzled (512 blocks).
  k_prep<<<2048 + 512, 256, 0, stream>>>(feats, Wu, Wl, Xb, WTu, WTl);

  // Stage 1: YU = Xb*Wu, YL = Xb*Wl (bf16, swizzled panels).
  k_stage1<<<dim3(DD / 128, BL * NL / 128, 2), 256, 0, stream>>>(Xb, WTu, WTl, YU, YL);

  // Stage 2: all 64 tiles per list in one dispatch.
  k_stage2<<<dim3(64, BL), 256, 0, stream>>>(Xb, YU, YL, bu, bl, out);
}